// Round 17
// baseline (250.986 us; speedup 1.0000x reference)
//
#include <hip/hip_runtime.h>

typedef unsigned short u16;
typedef unsigned int   u32;
typedef __bf16 bf16;
typedef __attribute__((ext_vector_type(8))) __bf16 bf16x8;
typedef __attribute__((ext_vector_type(4))) float  f32x4;

// ---------------- helpers ----------------

__device__ __forceinline__ u16 f2bf(float f) {
  u32 u = __float_as_uint(f);
  u32 r = (u + 0x7fffu + ((u >> 16) & 1u)) >> 16;   // RNE
  return (u16)r;
}

// global -> LDS direct, 16B per lane. LDS dest is wave-uniform base + lane*16.
__device__ __forceinline__ void gload_lds16(const void* g, void* l) {
  __builtin_amdgcn_global_load_lds((__attribute__((address_space(1))) u32*)g,
                                   (__attribute__((address_space(3))) u32*)l,
                                   16, 0, 0);
}

__device__ __forceinline__ u32 cvt_pk_bf16(float lo, float hi) {
  u32 r;
  asm("v_cvt_pk_bf16_f32 %0, %1, %2" : "=v"(r) : "v"(lo), "v"(hi));
  return r;
}

#define SCL_LOG2E 0.1803368801111204f  /* (1/sqrt(64)) * log2(e) */

// ---------------- fused f32 -> bf16 convert (x + all 4 weights, one launch) ---

__global__ __launch_bounds__(256) void cvt_all_kernel(const float* __restrict__ x,
                                                      const float* __restrict__ p0,
                                                      const float* __restrict__ p1,
                                                      const float* __restrict__ p2,
                                                      const float* __restrict__ p3,
                                                      u16* __restrict__ xo,
                                                      u16* o0, u16* o1, u16* o2, u16* o3) {
  const int bid = blockIdx.x;
  if (bid < 4096) {
    int i = bid * 256 + threadIdx.x;            // 1M threads, 2M float4s
    #pragma unroll
    for (int r = 0; r < 2; ++r, i += 1048576) {
      float4 v = ((const float4*)x)[i];
      uint2 o;
      o.x = (u32)f2bf(v.x) | ((u32)f2bf(v.y) << 16);
      o.y = (u32)f2bf(v.z) | ((u32)f2bf(v.w) << 16);
      ((uint2*)xo)[i] = o;
    }
  } else {
    const int wb = bid - 4096;
    const int which = wb >> 8;
    const float* in = which == 0 ? p0 : which == 1 ? p1 : which == 2 ? p2 : p3;
    u16* out = which == 0 ? o0 : which == 1 ? o1 : which == 2 ? o2 : o3;
    int i = (wb & 255) * 256 + threadIdx.x;
    #pragma unroll
    for (int r = 0; r < 4; ++r, i += 65536) {
      float4 v = ((const float4*)in)[i];
      uint2 o;
      o.x = (u32)f2bf(v.x) | ((u32)f2bf(v.y) << 16);
      o.y = (u32)f2bf(v.z) | ((u32)f2bf(v.w) << 16);
      ((uint2*)out)[i] = o;
    }
  }
}

// ---------------- GEMM core (2-slot dbuf + syncthreads — best measured) ------

#define GK 1024
#define GN 1024

// fused-serial QKV projection: grid 512 = EXACTLY 2 blocks/CU (no ragged tail;
// 1536-block version averaged 6/CU with ~4-5 resident -> partial second pass).
// Each block loops which = 0..2 over the SAME (tm,tn) tile, re-running the
// verified 2-slot K-loop per weight.  With the XCD swizzle each XCD's 64
// blocks span 8 tm values -> the A panel (2 MB) is L2-resident for the
// which=1,2 passes (A HBM traffic ~3x -> 1x).
//   Q -> plain [8192][1024] bf16 rows
//   K -> plain [8192][1024] bf16 rows, PRE-SCALED by SCL_LOG2E
//   V -> [BH][64][T] transposed, 8B-packed stores
__global__ __launch_bounds__(256) void gemm_qkv_kernel(const u16* __restrict__ A,
                                                       const u16* __restrict__ Wq,
                                                       const u16* __restrict__ Wk,
                                                       const u16* __restrict__ Wv,
                                                       const float* __restrict__ bq,
                                                       const float* __restrict__ bk,
                                                       const float* __restrict__ bv,
                                                       u16* __restrict__ Qo,
                                                       u16* __restrict__ Ko,
                                                       u16* __restrict__ Vo) {
  __shared__ u16 sA[2][128 * 32];
  __shared__ u16 sB[2][128 * 32];

  const int tid  = threadIdx.x;
  const int lane = tid & 63;
  const int w    = tid >> 6;
  const int wm   = w >> 1, wn = w & 1;
  // XCD-aware bijective swizzle: 512 = 8 x 64
  const int lid  = (blockIdx.x & 7) * 64 + (blockIdx.x >> 3);
  const int tn   = lid & 7;
  const int tm   = lid >> 3;
  const int m0   = tm * 128, n0 = tn * 128;
  const int rgrp = lane >> 4, rlo = lane & 15;

  const int c0 = (w * 2 + 0) * 64 + lane;
  const int c1 = (w * 2 + 1) * 64 + lane;
  const int r0 = c0 >> 2, col0 = (((c0 & 3) ^ (r0 & 3)) * 8);
  const int r1 = c1 >> 2, col1 = (((c1 & 3) ^ (r1 & 3)) * 8);
  const u16* aS0 = A + (size_t)(m0 + r0) * GK + col0;
  const u16* aS1 = A + (size_t)(m0 + r1) * GK + col1;

  for (int which = 0; which < 3; ++which) {
    const u16*  W    = which == 0 ? Wq : which == 1 ? Wk : Wv;
    const float* bias = which == 0 ? bq : which == 1 ? bk : bv;
    const u16* bS0 = W + (size_t)(n0 + r0) * GK + col0;
    const u16* bS1 = W + (size_t)(n0 + r1) * GK + col1;

    auto stage = [&](u16* dA, u16* dB, int kt) {
      int k0 = kt * 32;
      gload_lds16(aS0 + k0, dA + (w * 2 + 0) * 512);
      gload_lds16(aS1 + k0, dA + (w * 2 + 1) * 512);
      gload_lds16(bS0 + k0, dB + (w * 2 + 0) * 512);
      gload_lds16(bS1 + k0, dB + (w * 2 + 1) * 512);
    };

    f32x4 acc[4][4] = {};

    auto compute = [&](const u16* sAc, const u16* sBc) {
      bf16x8 a[4], b[4];
      #pragma unroll
      for (int i = 0; i < 4; ++i) {
        int row = wm * 64 + i * 16 + rlo;
        int cb  = rgrp ^ (row & 3);
        a[i] = *(const bf16x8*)&sAc[row * 32 + cb * 8];
      }
      #pragma unroll
      for (int j = 0; j < 4; ++j) {
        int row = wn * 64 + j * 16 + rlo;
        int cb  = rgrp ^ (row & 3);
        b[j] = *(const bf16x8*)&sBc[row * 32 + cb * 8];
      }
      #pragma unroll
      for (int i = 0; i < 4; ++i)
        #pragma unroll
        for (int j = 0; j < 4; ++j)
          acc[i][j] = __builtin_amdgcn_mfma_f32_16x16x32_bf16(a[i], b[j], acc[i][j], 0, 0, 0);
    };

    stage(sA[0], sB[0], 0);
    __syncthreads();

    for (int kt = 0; kt < GK / 32; kt += 2) {
      stage(sA[1], sB[1], kt + 1);
      compute(sA[0], sB[0]);
      __syncthreads();
      if (kt + 2 < GK / 32) stage(sA[0], sB[0], kt + 2);
      compute(sA[1], sB[1]);
      __syncthreads();
    }

    if (which <= 1) {
      u16* out = which == 0 ? Qo : Ko;
      const float scl = which == 0 ? 1.0f : SCL_LOG2E;
      #pragma unroll
      for (int i = 0; i < 4; ++i)
        #pragma unroll
        for (int j = 0; j < 4; ++j)
          #pragma unroll
          for (int r = 0; r < 4; ++r) {
            int m = m0 + wm * 64 + i * 16 + rgrp * 4 + r;
            int n = n0 + wn * 64 + j * 16 + rlo;
            float v = (acc[i][j][r] + bias[n]) * scl;
            out[(size_t)m * GN + n] = (u16)__builtin_bit_cast(u16, (bf16)v);
          }
    } else {
      #pragma unroll
      for (int i = 0; i < 4; ++i)
        #pragma unroll
        for (int j = 0; j < 4; ++j) {
          int mb = m0 + wm * 64 + i * 16 + rgrp * 4;
          int n  = n0 + wn * 64 + j * 16 + rlo;
          int b = mb >> 11, t = mb & 2047, h = n >> 6, hd = n & 63;
          float bv_ = bias[n];
          uint2 st;
          st.x = cvt_pk_bf16(acc[i][j][0] + bv_, acc[i][j][1] + bv_);
          st.y = cvt_pk_bf16(acc[i][j][2] + bv_, acc[i][j][3] + bv_);
          *(uint2*)&Vo[((size_t)(b * 16 + h) * 64 + hd) * 2048 + t] = st;
        }
    }
    // epilogue touches only registers/global; next which's stage into sA/sB[0]
    // is ordered by the K-loop's final __syncthreads (no remaining LDS readers).
  }
}

__global__ __launch_bounds__(256) void gemm_out_kernel(const u16* __restrict__ A,
                                                       const u16* __restrict__ W,
                                                       const float* __restrict__ bias,
                                                       float* __restrict__ Cout) {
  __shared__ u16 sA[2][128 * 32];
  __shared__ u16 sB[2][128 * 32];

  const int tid  = threadIdx.x;
  const int lane = tid & 63;
  const int w    = tid >> 6;
  const int wm   = w >> 1, wn = w & 1;
  const int lid  = (blockIdx.x & 7) * 64 + (blockIdx.x >> 3);
  const int tn   = lid & 7;
  const int tm   = lid >> 3;
  const int m0   = tm * 128, n0 = tn * 128;
  const int rgrp = lane >> 4, rlo = lane & 15;

  const int c0 = (w * 2 + 0) * 64 + lane;
  const int c1 = (w * 2 + 1) * 64 + lane;
  const int r0 = c0 >> 2, col0 = (((c0 & 3) ^ (r0 & 3)) * 8);
  const int r1 = c1 >> 2, col1 = (((c1 & 3) ^ (r1 & 3)) * 8);
  const u16* aS0 = A + (size_t)(m0 + r0) * GK + col0;
  const u16* aS1 = A + (size_t)(m0 + r1) * GK + col1;
  const u16* bS0 = W + (size_t)(n0 + r0) * GK + col0;
  const u16* bS1 = W + (size_t)(n0 + r1) * GK + col1;

  auto stage = [&](u16* dA, u16* dB, int kt) {
    int k0 = kt * 32;
    gload_lds16(aS0 + k0, dA + (w * 2 + 0) * 512);
    gload_lds16(aS1 + k0, dA + (w * 2 + 1) * 512);
    gload_lds16(bS0 + k0, dB + (w * 2 + 0) * 512);
    gload_lds16(bS1 + k0, dB + (w * 2 + 1) * 512);
  };

  f32x4 acc[4][4] = {};

  auto compute = [&](const u16* sAc, const u16* sBc) {
    bf16x8 a[4], b[4];
    #pragma unroll
    for (int i = 0; i < 4; ++i) {
      int row = wm * 64 + i * 16 + rlo;
      int cb  = rgrp ^ (row & 3);
      a[i] = *(const bf16x8*)&sAc[row * 32 + cb * 8];
    }
    #pragma unroll
    for (int j = 0; j < 4; ++j) {
      int row = wn * 64 + j * 16 + rlo;
      int cb  = rgrp ^ (row & 3);
      b[j] = *(const bf16x8*)&sBc[row * 32 + cb * 8];
    }
    #pragma unroll
    for (int i = 0; i < 4; ++i)
      #pragma unroll
      for (int j = 0; j < 4; ++j)
        acc[i][j] = __builtin_amdgcn_mfma_f32_16x16x32_bf16(a[i], b[j], acc[i][j], 0, 0, 0);
  };

  stage(sA[0], sB[0], 0);
  __syncthreads();

  for (int kt = 0; kt < GK / 32; kt += 2) {
    stage(sA[1], sB[1], kt + 1);
    compute(sA[0], sB[0]);
    __syncthreads();
    if (kt + 2 < GK / 32) stage(sA[0], sB[0], kt + 2);
    compute(sA[1], sB[1]);
    __syncthreads();
  }

  #pragma unroll
  for (int i = 0; i < 4; ++i)
    #pragma unroll
    for (int j = 0; j < 4; ++j)
      #pragma unroll
      for (int r = 0; r < 4; ++r) {
        int m = m0 + wm * 64 + i * 16 + rgrp * 4 + r;
        int n = n0 + wn * 64 + j * 16 + rlo;
        Cout[(size_t)m * GN + n] = acc[i][j][r] + bias[n];
      }
}

// ---------------- fused flash attention (8-wave blocks, exact residency) ------
// Unchanged from Round 16 (best measured: 85.5 us).

__global__ __launch_bounds__(512) void attn_kernel(const u16* __restrict__ Q,
                                                   const u16* __restrict__ K,
                                                   const u16* __restrict__ Vt,
                                                   bf16* __restrict__ O) {
  __shared__ u16 sK[2][64 * 64];
  __shared__ u16 sV[2][64 * 64];

  const int tid  = threadIdx.x;
  const int lane = tid & 63;
  const int w    = tid >> 6;              // 0..7
  const int rgrp = lane >> 4, rlo = lane & 15;
  // XCD-aware bijective swizzle: 1024 = 8 x 128
  const int bid  = (blockIdx.x & 7) * 128 + (blockIdx.x >> 3);
  const int qt   = bid & 15;              // 16 q-tiles of 128 rows
  const int bh   = bid >> 4;
  const int b    = bh >> 4, h = bh & 15;

  const u16* Qh = Q  + (size_t)b * 2048 * 1024 + h * 64;   // row stride 1024
  const u16* Kh = K  + (size_t)b * 2048 * 1024 + h * 64;   // row stride 1024
  const u16* Vh = Vt + (size_t)bh * 64 * 2048;             // row stride 2048

  // one 16B chunk per thread for K and V (chunk id = tid, 512 chunks = 8KB)
  const int cr = tid >> 3, cc = tid & 7;
  const int colc = ((cc ^ (cr & 7)) * 8);
  const u16* kb0 = Kh + (size_t)cr * 1024 + colc;
  const u16* vb0 = Vh + (size_t)cr * 2048 + colc;

  auto stage = [&](u16* dK, u16* dV) {
    gload_lds16(kb0, dK + w * 512);      // wave-uniform base + lane*16B = chunk tid
    gload_lds16(vb0, dV + w * 512);
    kb0 += 65536;   // 64 kv rows * 1024
    vb0 += 64;      // 64 kv cols
  };

  stage(sK[0], sV[0]);

  // Q B-fragments (one 16-row group per wave)
  bf16x8 bQ[2];
  {
    int q0 = qt * 128 + w * 16 + rlo;
    bQ[0] = *(const bf16x8*)&Qh[(size_t)q0 * 1024 + rgrp * 8];
    bQ[1] = *(const bf16x8*)&Qh[(size_t)q0 * 1024 + 32 + rgrp * 8];
  }

  bf16x8 vones;
  #pragma unroll
  for (int i = 0; i < 8; ++i) vones[i] = (bf16)1.0f;
  const f32x4 FZ = {0.f, 0.f, 0.f, 0.f};

  asm volatile("s_waitcnt vmcnt(0)" ::: "memory");
  __builtin_amdgcn_s_barrier();
  __builtin_amdgcn_sched_barrier(0);

  f32x4 lden = {};
  f32x4 o[4] = {};
  f32x4 sT[4];

  auto qk = [&](const u16* sKc) {
    __builtin_amdgcn_s_setprio(1);
    #pragma unroll
    for (int nt = 0; nt < 4; ++nt) {
      int row = nt * 16 + rlo;
      int cb0_ = (0 + rgrp) ^ (row & 7);
      int cb1_ = (4 + rgrp) ^ (row & 7);
      bf16x8 aK0 = *(const bf16x8*)&sKc[row * 64 + cb0_ * 8];
      bf16x8 aK1 = *(const bf16x8*)&sKc[row * 64 + cb1_ * 8];
      sT[nt] = __builtin_amdgcn_mfma_f32_16x16x32_bf16(aK0, bQ[0], FZ, 0, 0, 0);
      sT[nt] = __builtin_amdgcn_mfma_f32_16x16x32_bf16(aK1, bQ[1], sT[nt], 0, 0, 0);
    }
    __builtin_amdgcn_s_setprio(0);
  };

  auto smpv = [&](const u16* sVc) {
    #pragma unroll
    for (int nt = 0; nt < 4; ++nt)
      #pragma unroll
      for (int r = 0; r < 4; ++r)
        sT[nt][r] = __builtin_amdgcn_exp2f(sT[nt][r]);

    u32 pw[4][2];
    #pragma unroll
    for (int nt = 0; nt < 4; ++nt) {
      pw[nt][0] = cvt_pk_bf16(sT[nt][0], sT[nt][1]);
      pw[nt][1] = cvt_pk_bf16(sT[nt][2], sT[nt][3]);
    }
    bf16x8 bP[2];
    #pragma unroll
    for (int kk = 0; kk < 2; ++kk) {
      u32 a0 = pw[2 * kk][0], b0 = pw[2 * kk + 1][0];
      u32 a1 = pw[2 * kk][1], b1 = pw[2 * kk + 1][1];
      asm("v_permlane32_swap_b32 %0, %1" : "+v"(a0), "+v"(b0));
      asm("v_permlane16_swap_b32 %0, %1" : "+v"(a0), "+v"(b0));
      asm("v_permlane32_swap_b32 %0, %1" : "+v"(a1), "+v"(b1));
      asm("v_permlane16_swap_b32 %0, %1" : "+v"(a1), "+v"(b1));
      union { u32 u[4]; bf16x8 v; } fu;
      fu.u[0] = a0; fu.u[1] = a1; fu.u[2] = b0; fu.u[3] = b1;
      bP[kk] = fu.v;
    }

    __builtin_amdgcn_s_setprio(1);
    #pragma unroll
    for (int kk = 0; kk < 2; ++kk) {
      lden = __builtin_amdgcn_mfma_f32_16x16x32_bf16(vones, bP[kk], lden, 0, 0, 0);
      #pragma unroll
      for (int dt = 0; dt < 4; ++dt) {
        int rowv = dt * 16 + rlo;
        int cbv  = (kk * 4 + rgrp) ^ (rowv & 7);
        bf16x8 aV = *(const bf16x8*)&sVc[rowv * 64 + cbv * 8];
        o[dt] = __builtin_amdgcn_mfma_f32_16x16x32_bf16(aV, bP[kk], o[dt], 0, 0, 0);
      }
    }
    __builtin_amdgcn_s_setprio(0);
  };

  // single-barrier iteration: stage(t+1); qk(t); smpv(t); vmcnt(0); barrier
  auto iter = [&](const u16* sKc, const u16* sVc, u16* sKn, u16* sVn) {
    stage(sKn, sVn);
    qk(sKc);
    smpv(sVc);
    asm volatile("s_waitcnt vmcnt(0)" ::: "memory");
    __builtin_amdgcn_s_barrier();
    __builtin_amdgcn_sched_barrier(0);
  };

  for (int it = 0; it < 15; ++it) {
    iter(sK[0], sV[0], sK[1], sV[1]);
    iter(sK[1], sV[1], sK[0], sV[0]);
  }
  iter(sK[0], sV[0], sK[1], sV[1]);                   // t=30, stages tile 31

  // t = 31 (final): no stages, buffers already published by t=30's barrier
  qk(sK[1]);
  smpv(sV[1]);

  // finalize (denominator identical in every lden row: no shuffles)
  {
    const float inv = 1.0f / lden[0];
    const int tq = qt * 128 + w * 16 + rlo;
    #pragma unroll
    for (int dt = 0; dt < 4; ++dt) {
      uint2 st;
      st.x = cvt_pk_bf16(o[dt][0] * inv, o[dt][1] * inv);
      st.y = cvt_pk_bf16(o[dt][2] * inv, o[dt][3] * inv);
      *(uint2*)&O[((size_t)(b * 2048 + tq)) * 1024 + h * 64 + dt * 16 + rgrp * 4] = st;
    }
  }
}

// ---------------- launch ----------------

extern "C" void kernel_launch(void* const* d_in, const int* in_sizes, int n_in,
                              void* d_out, int out_size, void* d_ws, size_t ws_size,
                              hipStream_t stream) {
  const float* x  = (const float*)d_in[0];
  const float* Wq = (const float*)d_in[1];
  const float* bq = (const float*)d_in[2];
  const float* Wk = (const float*)d_in[3];
  const float* bk = (const float*)d_in[4];
  const float* Wv = (const float*)d_in[5];
  const float* bv = (const float*)d_in[6];
  const float* Wo = (const float*)d_in[7];
  const float* bo = (const float*)d_in[8];

  char* ws = (char*)d_ws;
  u16* xb  = (u16*)(ws);                      // 16 MiB  [8192][1024]
  u16* Wqb = (u16*)(ws + 16777216);           //  2 MiB
  u16* Wkb = (u16*)(ws + 18874368);
  u16* Wvb = (u16*)(ws + 20971520);
  u16* Wob = (u16*)(ws + 23068672);
  u16* Qb  = (u16*)(ws + 25165824);           // 16 MiB  [8192][1024]
  u16* Kb  = (u16*)(ws + 41943040);           // 16 MiB  [8192][1024] (pre-scaled)
  u16* Vtb = (u16*)(ws + 58720256);           // 16 MiB  [BH][64][T]
  u16* Ab  = (u16*)(ws + 75497472);           // 16 MiB  [B][T][1024]

  cvt_all_kernel<<<5120, 256, 0, stream>>>(x, Wq, Wk, Wv, Wo, xb, Wqb, Wkb, Wvb, Wob);

  gemm_qkv_kernel<<<512, 256, 0, stream>>>(xb, Wqb, Wkb, Wvb, bq, bk, bv, Qb, Kb, Vtb);

  attn_kernel<<<1024, 512, 0, stream>>>(Qb, Kb, Vtb, (bf16*)Ab);

  gemm_out_kernel<<<512, 256, 0, stream>>>(Ab, Wob, bo, (float*)d_out);
}

// Round 18
// 203.487 us; speedup vs baseline: 1.2334x; 1.2334x over previous
//
#include <hip/hip_runtime.h>

typedef unsigned short u16;
typedef unsigned int   u32;
typedef __bf16 bf16;
typedef __attribute__((ext_vector_type(8))) __bf16 bf16x8;
typedef __attribute__((ext_vector_type(4))) float  f32x4;

// ---------------- helpers ----------------

__device__ __forceinline__ u16 f2bf(float f) {
  u32 u = __float_as_uint(f);
  u32 r = (u + 0x7fffu + ((u >> 16) & 1u)) >> 16;   // RNE
  return (u16)r;
}

// global -> LDS direct, 16B per lane. LDS dest is wave-uniform base + lane*16.
__device__ __forceinline__ void gload_lds16(const void* g, void* l) {
  __builtin_amdgcn_global_load_lds((__attribute__((address_space(1))) u32*)g,
                                   (__attribute__((address_space(3))) u32*)l,
                                   16, 0, 0);
}

__device__ __forceinline__ u32 cvt_pk_bf16(float lo, float hi) {
  u32 r;
  asm("v_cvt_pk_bf16_f32 %0, %1, %2" : "=v"(r) : "v"(lo), "v"(hi));
  return r;
}

#define SCL_LOG2E 0.1803368801111204f  /* (1/sqrt(64)) * log2(e) */

// ---------------- fused f32 -> bf16 convert (x + all 4 weights, one launch) ---

__global__ __launch_bounds__(256) void cvt_all_kernel(const float* __restrict__ x,
                                                      const float* __restrict__ p0,
                                                      const float* __restrict__ p1,
                                                      const float* __restrict__ p2,
                                                      const float* __restrict__ p3,
                                                      u16* __restrict__ xo,
                                                      u16* o0, u16* o1, u16* o2, u16* o3) {
  const int bid = blockIdx.x;
  if (bid < 4096) {
    int i = bid * 256 + threadIdx.x;            // 1M threads, 2M float4s
    #pragma unroll
    for (int r = 0; r < 2; ++r, i += 1048576) {
      float4 v = ((const float4*)x)[i];
      uint2 o;
      o.x = (u32)f2bf(v.x) | ((u32)f2bf(v.y) << 16);
      o.y = (u32)f2bf(v.z) | ((u32)f2bf(v.w) << 16);
      ((uint2*)xo)[i] = o;
    }
  } else {
    const int wb = bid - 4096;
    const int which = wb >> 8;
    const float* in = which == 0 ? p0 : which == 1 ? p1 : which == 2 ? p2 : p3;
    u16* out = which == 0 ? o0 : which == 1 ? o1 : which == 2 ? o2 : o3;
    int i = (wb & 255) * 256 + threadIdx.x;
    #pragma unroll
    for (int r = 0; r < 4; ++r, i += 65536) {
      float4 v = ((const float4*)in)[i];
      uint2 o;
      o.x = (u32)f2bf(v.x) | ((u32)f2bf(v.y) << 16);
      o.y = (u32)f2bf(v.z) | ((u32)f2bf(v.w) << 16);
      ((uint2*)out)[i] = o;
    }
  }
}

// ---------------- GEMM core (2-slot dbuf; bank-conflict-fixed swizzle) --------
// C[m,n] = sum_k A[m,k]*W[n,k] + bias[n]; M=8192, N=1024 (per W), K=1024.
// 128x128 tile, BK=32, 4 waves (2x2), 16x16x32 MFMA, double-buffered LDS.
// SWIZZLE FIX (R18): S(row) = (row>>1)&3 (was row&3).  Bank of a chunk is
// 16*(row&1) + 4*cb; with cb = rgrp ^ ((row>>1)&3) the pair (row&1,(row>>1)&3)
// spans all 8 combos over a 16-lane row-group -> 8 distinct banks, 2-way
// aliasing (free) instead of the measured 4-way (6.3M conflict cycles).
// Same involution applied to staging source column and read side.

#define GK 1024
#define GN 1024

__global__ __launch_bounds__(256) void gemm_qkv_kernel(const u16* __restrict__ A,
                                                       const u16* __restrict__ Wq,
                                                       const u16* __restrict__ Wk,
                                                       const u16* __restrict__ Wv,
                                                       const float* __restrict__ bq,
                                                       const float* __restrict__ bk,
                                                       const float* __restrict__ bv,
                                                       u16* __restrict__ Qo,
                                                       u16* __restrict__ Ko,
                                                       u16* __restrict__ Vo) {
  __shared__ u16 sA[2][128 * 32];
  __shared__ u16 sB[2][128 * 32];

  const int tid  = threadIdx.x;
  const int lane = tid & 63;
  const int w    = tid >> 6;
  const int wm   = w >> 1, wn = w & 1;
  const int lid  = (blockIdx.x & 7) * 192 + (blockIdx.x >> 3);
  const int which = lid >> 9;            // 0..2
  const int sub   = lid & 511;
  const u16*  W    = which == 0 ? Wq : which == 1 ? Wk : Wv;
  const float* bias = which == 0 ? bq : which == 1 ? bk : bv;
  const int tn   = sub & 7;
  const int tm   = sub >> 3;
  const int m0   = tm * 128, n0 = tn * 128;
  const int rgrp = lane >> 4, rlo = lane & 15;

  const int c0 = (w * 2 + 0) * 64 + lane;
  const int c1 = (w * 2 + 1) * 64 + lane;
  const int r0 = c0 >> 2, col0 = (((c0 & 3) ^ ((r0 >> 1) & 3)) * 8);
  const int r1 = c1 >> 2, col1 = (((c1 & 3) ^ ((r1 >> 1) & 3)) * 8);
  const u16* aS0 = A + (size_t)(m0 + r0) * GK + col0;
  const u16* aS1 = A + (size_t)(m0 + r1) * GK + col1;
  const u16* bS0 = W + (size_t)(n0 + r0) * GK + col0;
  const u16* bS1 = W + (size_t)(n0 + r1) * GK + col1;

  auto stage = [&](u16* dA, u16* dB, int kt) {
    int k0 = kt * 32;
    gload_lds16(aS0 + k0, dA + (w * 2 + 0) * 512);
    gload_lds16(aS1 + k0, dA + (w * 2 + 1) * 512);
    gload_lds16(bS0 + k0, dB + (w * 2 + 0) * 512);
    gload_lds16(bS1 + k0, dB + (w * 2 + 1) * 512);
  };

  f32x4 acc[4][4] = {};

  auto compute = [&](const u16* sAc, const u16* sBc) {
    bf16x8 a[4], b[4];
    #pragma unroll
    for (int i = 0; i < 4; ++i) {
      int row = wm * 64 + i * 16 + rlo;
      int cb  = rgrp ^ ((row >> 1) & 3);
      a[i] = *(const bf16x8*)&sAc[row * 32 + cb * 8];
    }
    #pragma unroll
    for (int j = 0; j < 4; ++j) {
      int row = wn * 64 + j * 16 + rlo;
      int cb  = rgrp ^ ((row >> 1) & 3);
      b[j] = *(const bf16x8*)&sBc[row * 32 + cb * 8];
    }
    #pragma unroll
    for (int i = 0; i < 4; ++i)
      #pragma unroll
      for (int j = 0; j < 4; ++j)
        acc[i][j] = __builtin_amdgcn_mfma_f32_16x16x32_bf16(a[i], b[j], acc[i][j], 0, 0, 0);
  };

  stage(sA[0], sB[0], 0);
  __syncthreads();

  for (int kt = 0; kt < GK / 32; kt += 2) {
    stage(sA[1], sB[1], kt + 1);
    compute(sA[0], sB[0]);
    __syncthreads();
    if (kt + 2 < GK / 32) stage(sA[0], sB[0], kt + 2);
    compute(sA[1], sB[1]);
    __syncthreads();
  }

  if (which <= 1) {
    u16* out = which == 0 ? Qo : Ko;
    const float scl = which == 0 ? 1.0f : SCL_LOG2E;
    #pragma unroll
    for (int i = 0; i < 4; ++i)
      #pragma unroll
      for (int j = 0; j < 4; ++j)
        #pragma unroll
        for (int r = 0; r < 4; ++r) {
          int m = m0 + wm * 64 + i * 16 + rgrp * 4 + r;
          int n = n0 + wn * 64 + j * 16 + rlo;
          float v = (acc[i][j][r] + bias[n]) * scl;
          out[(size_t)m * GN + n] = (u16)__builtin_bit_cast(u16, (bf16)v);
        }
  } else {
    #pragma unroll
    for (int i = 0; i < 4; ++i)
      #pragma unroll
      for (int j = 0; j < 4; ++j) {
        int mb = m0 + wm * 64 + i * 16 + rgrp * 4;
        int n  = n0 + wn * 64 + j * 16 + rlo;
        int b = mb >> 11, t = mb & 2047, h = n >> 6, hd = n & 63;
        float bv_ = bias[n];
        uint2 st;
        st.x = cvt_pk_bf16(acc[i][j][0] + bv_, acc[i][j][1] + bv_);
        st.y = cvt_pk_bf16(acc[i][j][2] + bv_, acc[i][j][3] + bv_);
        *(uint2*)&Vo[((size_t)(b * 16 + h) * 64 + hd) * 2048 + t] = st;
      }
  }
}

__global__ __launch_bounds__(256) void gemm_out_kernel(const u16* __restrict__ A,
                                                       const u16* __restrict__ W,
                                                       const float* __restrict__ bias,
                                                       float* __restrict__ Cout) {
  __shared__ u16 sA[2][128 * 32];
  __shared__ u16 sB[2][128 * 32];

  const int tid  = threadIdx.x;
  const int lane = tid & 63;
  const int w    = tid >> 6;
  const int wm   = w >> 1, wn = w & 1;
  const int lid  = (blockIdx.x & 7) * 64 + (blockIdx.x >> 3);
  const int tn   = lid & 7;
  const int tm   = lid >> 3;
  const int m0   = tm * 128, n0 = tn * 128;
  const int rgrp = lane >> 4, rlo = lane & 15;

  const int c0 = (w * 2 + 0) * 64 + lane;
  const int c1 = (w * 2 + 1) * 64 + lane;
  const int r0 = c0 >> 2, col0 = (((c0 & 3) ^ ((r0 >> 1) & 3)) * 8);
  const int r1 = c1 >> 2, col1 = (((c1 & 3) ^ ((r1 >> 1) & 3)) * 8);
  const u16* aS0 = A + (size_t)(m0 + r0) * GK + col0;
  const u16* aS1 = A + (size_t)(m0 + r1) * GK + col1;
  const u16* bS0 = W + (size_t)(n0 + r0) * GK + col0;
  const u16* bS1 = W + (size_t)(n0 + r1) * GK + col1;

  auto stage = [&](u16* dA, u16* dB, int kt) {
    int k0 = kt * 32;
    gload_lds16(aS0 + k0, dA + (w * 2 + 0) * 512);
    gload_lds16(aS1 + k0, dA + (w * 2 + 1) * 512);
    gload_lds16(bS0 + k0, dB + (w * 2 + 0) * 512);
    gload_lds16(bS1 + k0, dB + (w * 2 + 1) * 512);
  };

  f32x4 acc[4][4] = {};

  auto compute = [&](const u16* sAc, const u16* sBc) {
    bf16x8 a[4], b[4];
    #pragma unroll
    for (int i = 0; i < 4; ++i) {
      int row = wm * 64 + i * 16 + rlo;
      int cb  = rgrp ^ ((row >> 1) & 3);
      a[i] = *(const bf16x8*)&sAc[row * 32 + cb * 8];
    }
    #pragma unroll
    for (int j = 0; j < 4; ++j) {
      int row = wn * 64 + j * 16 + rlo;
      int cb  = rgrp ^ ((row >> 1) & 3);
      b[j] = *(const bf16x8*)&sBc[row * 32 + cb * 8];
    }
    #pragma unroll
    for (int i = 0; i < 4; ++i)
      #pragma unroll
      for (int j = 0; j < 4; ++j)
        acc[i][j] = __builtin_amdgcn_mfma_f32_16x16x32_bf16(a[i], b[j], acc[i][j], 0, 0, 0);
  };

  stage(sA[0], sB[0], 0);
  __syncthreads();

  for (int kt = 0; kt < GK / 32; kt += 2) {
    stage(sA[1], sB[1], kt + 1);
    compute(sA[0], sB[0]);
    __syncthreads();
    if (kt + 2 < GK / 32) stage(sA[0], sB[0], kt + 2);
    compute(sA[1], sB[1]);
    __syncthreads();
  }

  #pragma unroll
  for (int i = 0; i < 4; ++i)
    #pragma unroll
    for (int j = 0; j < 4; ++j)
      #pragma unroll
      for (int r = 0; r < 4; ++r) {
        int m = m0 + wm * 64 + i * 16 + rgrp * 4 + r;
        int n = n0 + wn * 64 + j * 16 + rlo;
        Cout[(size_t)m * GN + n] = acc[i][j][r] + bias[n];
      }
}

// ---------------- fused flash attention (8-wave blocks, exact residency) ------
// Unchanged from Round 16 (best measured: 85.5 us).

__global__ __launch_bounds__(512) void attn_kernel(const u16* __restrict__ Q,
                                                   const u16* __restrict__ K,
                                                   const u16* __restrict__ Vt,
                                                   bf16* __restrict__ O) {
  __shared__ u16 sK[2][64 * 64];
  __shared__ u16 sV[2][64 * 64];

  const int tid  = threadIdx.x;
  const int lane = tid & 63;
  const int w    = tid >> 6;              // 0..7
  const int rgrp = lane >> 4, rlo = lane & 15;
  // XCD-aware bijective swizzle: 1024 = 8 x 128
  const int bid  = (blockIdx.x & 7) * 128 + (blockIdx.x >> 3);
  const int qt   = bid & 15;              // 16 q-tiles of 128 rows
  const int bh   = bid >> 4;
  const int b    = bh >> 4, h = bh & 15;

  const u16* Qh = Q  + (size_t)b * 2048 * 1024 + h * 64;   // row stride 1024
  const u16* Kh = K  + (size_t)b * 2048 * 1024 + h * 64;   // row stride 1024
  const u16* Vh = Vt + (size_t)bh * 64 * 2048;             // row stride 2048

  // one 16B chunk per thread for K and V (chunk id = tid, 512 chunks = 8KB)
  const int cr = tid >> 3, cc = tid & 7;
  const int colc = ((cc ^ (cr & 7)) * 8);
  const u16* kb0 = Kh + (size_t)cr * 1024 + colc;
  const u16* vb0 = Vh + (size_t)cr * 2048 + colc;

  auto stage = [&](u16* dK, u16* dV) {
    gload_lds16(kb0, dK + w * 512);      // wave-uniform base + lane*16B = chunk tid
    gload_lds16(vb0, dV + w * 512);
    kb0 += 65536;   // 64 kv rows * 1024
    vb0 += 64;      // 64 kv cols
  };

  stage(sK[0], sV[0]);

  // Q B-fragments (one 16-row group per wave)
  bf16x8 bQ[2];
  {
    int q0 = qt * 128 + w * 16 + rlo;
    bQ[0] = *(const bf16x8*)&Qh[(size_t)q0 * 1024 + rgrp * 8];
    bQ[1] = *(const bf16x8*)&Qh[(size_t)q0 * 1024 + 32 + rgrp * 8];
  }

  bf16x8 vones;
  #pragma unroll
  for (int i = 0; i < 8; ++i) vones[i] = (bf16)1.0f;
  const f32x4 FZ = {0.f, 0.f, 0.f, 0.f};

  asm volatile("s_waitcnt vmcnt(0)" ::: "memory");
  __builtin_amdgcn_s_barrier();
  __builtin_amdgcn_sched_barrier(0);

  f32x4 lden = {};
  f32x4 o[4] = {};
  f32x4 sT[4];

  auto qk = [&](const u16* sKc) {
    __builtin_amdgcn_s_setprio(1);
    #pragma unroll
    for (int nt = 0; nt < 4; ++nt) {
      int row = nt * 16 + rlo;
      int cb0_ = (0 + rgrp) ^ (row & 7);
      int cb1_ = (4 + rgrp) ^ (row & 7);
      bf16x8 aK0 = *(const bf16x8*)&sKc[row * 64 + cb0_ * 8];
      bf16x8 aK1 = *(const bf16x8*)&sKc[row * 64 + cb1_ * 8];
      sT[nt] = __builtin_amdgcn_mfma_f32_16x16x32_bf16(aK0, bQ[0], FZ, 0, 0, 0);
      sT[nt] = __builtin_amdgcn_mfma_f32_16x16x32_bf16(aK1, bQ[1], sT[nt], 0, 0, 0);
    }
    __builtin_amdgcn_s_setprio(0);
  };

  auto smpv = [&](const u16* sVc) {
    #pragma unroll
    for (int nt = 0; nt < 4; ++nt)
      #pragma unroll
      for (int r = 0; r < 4; ++r)
        sT[nt][r] = __builtin_amdgcn_exp2f(sT[nt][r]);

    u32 pw[4][2];
    #pragma unroll
    for (int nt = 0; nt < 4; ++nt) {
      pw[nt][0] = cvt_pk_bf16(sT[nt][0], sT[nt][1]);
      pw[nt][1] = cvt_pk_bf16(sT[nt][2], sT[nt][3]);
    }
    bf16x8 bP[2];
    #pragma unroll
    for (int kk = 0; kk < 2; ++kk) {
      u32 a0 = pw[2 * kk][0], b0 = pw[2 * kk + 1][0];
      u32 a1 = pw[2 * kk][1], b1 = pw[2 * kk + 1][1];
      asm("v_permlane32_swap_b32 %0, %1" : "+v"(a0), "+v"(b0));
      asm("v_permlane16_swap_b32 %0, %1" : "+v"(a0), "+v"(b0));
      asm("v_permlane32_swap_b32 %0, %1" : "+v"(a1), "+v"(b1));
      asm("v_permlane16_swap_b32 %0, %1" : "+v"(a1), "+v"(b1));
      union { u32 u[4]; bf16x8 v; } fu;
      fu.u[0] = a0; fu.u[1] = a1; fu.u[2] = b0; fu.u[3] = b1;
      bP[kk] = fu.v;
    }

    __builtin_amdgcn_s_setprio(1);
    #pragma unroll
    for (int kk = 0; kk < 2; ++kk) {
      lden = __builtin_amdgcn_mfma_f32_16x16x32_bf16(vones, bP[kk], lden, 0, 0, 0);
      #pragma unroll
      for (int dt = 0; dt < 4; ++dt) {
        int rowv = dt * 16 + rlo;
        int cbv  = (kk * 4 + rgrp) ^ (rowv & 7);
        bf16x8 aV = *(const bf16x8*)&sVc[rowv * 64 + cbv * 8];
        o[dt] = __builtin_amdgcn_mfma_f32_16x16x32_bf16(aV, bP[kk], o[dt], 0, 0, 0);
      }
    }
    __builtin_amdgcn_s_setprio(0);
  };

  // single-barrier iteration: stage(t+1); qk(t); smpv(t); vmcnt(0); barrier
  auto iter = [&](const u16* sKc, const u16* sVc, u16* sKn, u16* sVn) {
    stage(sKn, sVn);
    qk(sKc);
    smpv(sVc);
    asm volatile("s_waitcnt vmcnt(0)" ::: "memory");
    __builtin_amdgcn_s_barrier();
    __builtin_amdgcn_sched_barrier(0);
  };

  for (int it = 0; it < 15; ++it) {
    iter(sK[0], sV[0], sK[1], sV[1]);
    iter(sK[1], sV[1], sK[0], sV[0]);
  }
  iter(sK[0], sV[0], sK[1], sV[1]);                   // t=30, stages tile 31

  // t = 31 (final): no stages, buffers already published by t=30's barrier
  qk(sK[1]);
  smpv(sV[1]);

  // finalize (denominator identical in every lden row: no shuffles)
  {
    const float inv = 1.0f / lden[0];
    const int tq = qt * 128 + w * 16 + rlo;
    #pragma unroll
    for (int dt = 0; dt < 4; ++dt) {
      uint2 st;
      st.x = cvt_pk_bf16(o[dt][0] * inv, o[dt][1] * inv);
      st.y = cvt_pk_bf16(o[dt][2] * inv, o[dt][3] * inv);
      *(uint2*)&O[((size_t)(b * 2048 + tq)) * 1024 + h * 64 + dt * 16 + rgrp * 4] = st;
    }
  }
}

// ---------------- launch ----------------

extern "C" void kernel_launch(void* const* d_in, const int* in_sizes, int n_in,
                              void* d_out, int out_size, void* d_ws, size_t ws_size,
                              hipStream_t stream) {
  const float* x  = (const float*)d_in[0];
  const float* Wq = (const float*)d_in[1];
  const float* bq = (const float*)d_in[2];
  const float* Wk = (const float*)d_in[3];
  const float* bk = (const float*)d_in[4];
  const float* Wv = (const float*)d_in[5];
  const float* bv = (const float*)d_in[6];
  const float* Wo = (const float*)d_in[7];
  const float* bo = (const float*)d_in[8];

  char* ws = (char*)d_ws;
  u16* xb  = (u16*)(ws);                      // 16 MiB  [8192][1024]
  u16* Wqb = (u16*)(ws + 16777216);           //  2 MiB
  u16* Wkb = (u16*)(ws + 18874368);
  u16* Wvb = (u16*)(ws + 20971520);
  u16* Wob = (u16*)(ws + 23068672);
  u16* Qb  = (u16*)(ws + 25165824);           // 16 MiB  [8192][1024]
  u16* Kb  = (u16*)(ws + 41943040);           // 16 MiB  [8192][1024] (pre-scaled)
  u16* Vtb = (u16*)(ws + 58720256);           // 16 MiB  [BH][64][T]
  u16* Ab  = (u16*)(ws + 75497472);           // 16 MiB  [B][T][1024]

  cvt_all_kernel<<<5120, 256, 0, stream>>>(x, Wq, Wk, Wv, Wo, xb, Wqb, Wkb, Wvb, Wob);

  gemm_qkv_kernel<<<1536, 256, 0, stream>>>(xb, Wqb, Wkb, Wvb, bq, bk, bv, Qb, Kb, Vtb);

  attn_kernel<<<1024, 512, 0, stream>>>(Qb, Kb, Vtb, (bf16*)Ab);

  gemm_out_kernel<<<512, 256, 0, stream>>>(Ab, Wob, bo, (float*)d_out);
}